// Round 4
// baseline (213.950 us; speedup 1.0000x reference)
//
#include <hip/hip_runtime.h>
#include <cstdint>

#define BATCH 4096
#define IN_DIM 1024
#define HID 2048
#define OUT_DIM 10
#define NTASKS 10

typedef __bf16 bf16x8 __attribute__((ext_vector_type(8)));
typedef float f32x4 __attribute__((ext_vector_type(4)));
typedef __attribute__((address_space(3))) uint8_t lds_u8;
typedef const __attribute__((address_space(1))) uint8_t glb_u8;

__device__ __forceinline__ unsigned short f2bf(float f) {
    uint32_t u = __builtin_bit_cast(uint32_t, f);
    u += 0x7fffu + ((u >> 16) & 1u);   // round-to-nearest-even
    return (unsigned short)(u >> 16);
}
__device__ __forceinline__ float bf2f(unsigned short h) {
    uint32_t u = ((uint32_t)h) << 16;
    return __builtin_bit_cast(float, u);
}

// ---------------- transform kernels ----------------
// 4x unrolled, all 12 loads issued before any use -> ~12KB in flight per wave
// (round-3 profile: VGPR_Count=12 serialized one 3KB burst per latency -> 1.7 TB/s).
// Grids are sized exactly: n4 % 1024 == 0 for every call site, no guards.

__global__ __launch_bounds__(256) void bl_transform(
    const float4* __restrict__ mu, const float4* __restrict__ ls,
    const float4* __restrict__ eps, ushort4* __restrict__ out)
{
    const int i0 = blockIdx.x * 1024 + threadIdx.x;
    const float4 m0 = mu[i0], m1 = mu[i0 + 256], m2 = mu[i0 + 512], m3 = mu[i0 + 768];
    const float4 l0 = ls[i0], l1 = ls[i0 + 256], l2 = ls[i0 + 512], l3 = ls[i0 + 768];
    const float4 e0 = eps[i0], e1 = eps[i0 + 256], e2 = eps[i0 + 512], e3 = eps[i0 + 768];
    ushort4 r0, r1, r2, r3;
    r0.x = f2bf(m0.x + __expf(l0.x) * e0.x); r0.y = f2bf(m0.y + __expf(l0.y) * e0.y);
    r0.z = f2bf(m0.z + __expf(l0.z) * e0.z); r0.w = f2bf(m0.w + __expf(l0.w) * e0.w);
    r1.x = f2bf(m1.x + __expf(l1.x) * e1.x); r1.y = f2bf(m1.y + __expf(l1.y) * e1.y);
    r1.z = f2bf(m1.z + __expf(l1.z) * e1.z); r1.w = f2bf(m1.w + __expf(l1.w) * e1.w);
    r2.x = f2bf(m2.x + __expf(l2.x) * e2.x); r2.y = f2bf(m2.y + __expf(l2.y) * e2.y);
    r2.z = f2bf(m2.z + __expf(l2.z) * e2.z); r2.w = f2bf(m2.w + __expf(l2.w) * e2.w);
    r3.x = f2bf(m3.x + __expf(l3.x) * e3.x); r3.y = f2bf(m3.y + __expf(l3.y) * e3.y);
    r3.z = f2bf(m3.z + __expf(l3.z) * e3.z); r3.w = f2bf(m3.w + __expf(l3.w) * e3.w);
    out[i0]       = r0;
    out[i0 + 256] = r1;
    out[i0 + 512] = r2;
    out[i0 + 768] = r3;
}

__global__ __launch_bounds__(256) void bl_cvt(
    const float4* __restrict__ in, ushort4* __restrict__ out)
{
    const int i0 = blockIdx.x * 1024 + threadIdx.x;
    const float4 v0 = in[i0], v1 = in[i0 + 256], v2 = in[i0 + 512], v3 = in[i0 + 768];
    ushort4 r0, r1, r2, r3;
    r0.x = f2bf(v0.x); r0.y = f2bf(v0.y); r0.z = f2bf(v0.z); r0.w = f2bf(v0.w);
    r1.x = f2bf(v1.x); r1.y = f2bf(v1.y); r1.z = f2bf(v1.z); r1.w = f2bf(v1.w);
    r2.x = f2bf(v2.x); r2.y = f2bf(v2.y); r2.z = f2bf(v2.z); r2.w = f2bf(v2.w);
    r3.x = f2bf(v3.x); r3.y = f2bf(v3.y); r3.z = f2bf(v3.z); r3.w = f2bf(v3.w);
    out[i0]       = r0;
    out[i0 + 256] = r1;
    out[i0 + 512] = r2;
    out[i0 + 768] = r3;
}

__global__ __launch_bounds__(256) void bl_small(
    const float* __restrict__ mu_b0, const float* __restrict__ ls_b0, const float* __restrict__ eps_b0,
    const float* __restrict__ mu_b,  const float* __restrict__ ls_b,  const float* __restrict__ eps_b,
    const float* __restrict__ mu_hw, const float* __restrict__ ls_hw, const float* __restrict__ eps_hw,
    const float* __restrict__ mu_hb, const float* __restrict__ ls_hb, const float* __restrict__ eps_hb,
    float* __restrict__ b_all, float* __restrict__ hw, float* __restrict__ hb)
{
    const int total = HID + 3*HID + NTASKS*OUT_DIM*HID + NTASKS*OUT_DIM;
    int i = blockIdx.x * blockDim.x + threadIdx.x;
    const int stride = gridDim.x * blockDim.x;
    for (; i < total; i += stride) {
        if (i < HID) {
            b_all[i] = mu_b0[i] + __expf(ls_b0[i]) * eps_b0[i];
        } else if (i < 4*HID) {
            const int j = i - HID;
            b_all[HID + j] = mu_b[j] + __expf(ls_b[j]) * eps_b[j];
        } else if (i < 4*HID + NTASKS*OUT_DIM*HID) {
            const int j = i - 4*HID;
            hw[j] = mu_hw[j] + __expf(ls_hw[j]) * eps_hw[j];
        } else {
            const int j = i - (4*HID + NTASKS*OUT_DIM*HID);
            hb[j] = mu_hb[j] + __expf(ls_hb[j]) * eps_hb[j];
        }
    }
}

// ---------------- GEMM: C[4096,2048] = relu(A[4096,K] @ B[2048,K]^T + bias)
// BM=256 BN=128 BK=64, 8 waves (4M x 2N, 64x64 each), double-buffered LDS (96KB),
// 4 phases per K-tile. Barriers are inline-asm s_barrier WITH "memory" clobber
// (the s_barrier builtin is IntrNoMem -> round-2 replay race). Full-drain points
// use __syncthreads(). Both next-tile stage halves issue in phases 0/1 so the
// end-of-tile vmcnt(0) drain has ~3 phases of MFMA cover.
#define BAR()        asm volatile("s_barrier" ::: "memory")
#define WAIT_LGKM0() do { asm volatile("s_waitcnt lgkmcnt(0)" ::: "memory"); __builtin_amdgcn_sched_barrier(0); } while (0)
#define RD_A(m, o)   (*(const bf16x8*)(ldsb + acur + (o) + (m)*2048))
#define RD_B(n, o)   (*(const bf16x8*)(ldsb + bcur + (o) + (n)*2048))
#define MFMA(d, va, vb) d = __builtin_amdgcn_mfma_f32_16x16x32_bf16(va, vb, d, 0, 0, 0)
#define STAGEI(i, kel, sl) \
    __builtin_amdgcn_global_load_lds((glb_u8*)(gsrc[i] + (kel)), \
        (lds_u8*)(ldsb + ldst[i] + (uint32_t)(sl) * smul[i]), 16, 0, 0)

__global__ __launch_bounds__(512, 2) void bl_gemm(
    const unsigned short* __restrict__ A,   // [4096][K] bf16
    const unsigned short* __restrict__ B,   // [2048][K] bf16
    const float* __restrict__ bias,         // [2048]
    unsigned short* __restrict__ C,         // [4096][2048] bf16
    int K)
{
    // LDS: A slots @0 and @32768 bytes (256x64 bf16 each); B slots @65536, @81920 (128x64)
    __shared__ unsigned short lds[49152];   // 96 KB
    uint8_t* ldsb = (uint8_t*)lds;

    const int tid  = threadIdx.x;
    const int wave = tid >> 6;
    const int lane = tid & 63;
    // bijective XCD swizzle: nwg=256, 8 XCDs, 32 contiguous wgs per XCD
    const int swz = ((blockIdx.x & 7) << 5) | (blockIdx.x >> 3);
    const int bm = swz >> 4;        // 0..15  (M tiles of 256)
    const int bn = swz & 15;        // 0..15  (N tiles of 128)
    const int wr = wave >> 1;       // 0..3 -> m offset wr*64
    const int wc = wave & 1;        // 0..1 -> n offset wc*64

    // ---- staging setup: 48 chunks/tile (32 A + 16 B), 6 per wave ----
    // chunk c covers LDS linear bytes [c*1024, +1024) of its region = rows c*8..c*8+7.
    // lane l -> row = c*8 + (l>>3), 16B slot (l&7); swizzled source slot = (l&7)^(l>>3).
    const int lr8 = lane >> 3;
    const int ss  = (lane & 7) ^ lr8;
    const unsigned short* gsrc[6];
    uint32_t ldst[6], smul[6];
    #pragma unroll
    for (int i = 0; i < 6; ++i) {
        const int c = wave * 6 + i;
        if (c < 32) {
            gsrc[i] = A + (size_t)(bm * 256 + c * 8 + lr8) * K + ss * 8;
            ldst[i] = (uint32_t)c * 1024u;
            smul[i] = 32768u;
        } else {
            gsrc[i] = B + (size_t)(bn * 128 + (c - 32) * 8 + lr8) * K + ss * 8;
            ldst[i] = 65536u + (uint32_t)(c - 32) * 1024u;
            smul[i] = 16384u;
        }
    }

    // ---- fragment-read offsets (row stride 128B, slot ^= row&7 swizzle) ----
    const int rA = wr * 64 + (lane & 15);
    const int rB = wc * 64 + (lane & 15);
    const int ks = lane >> 4;                    // 16B slot within 32-wide k-block
    const uint32_t aoff0 = (uint32_t)(rA * 128 + ((ks       ^ (rA & 7)) * 16));
    const uint32_t aoff1 = (uint32_t)(rA * 128 + (((4 | ks) ^ (rA & 7)) * 16));
    const uint32_t boff0 = (uint32_t)(rB * 128 + ((ks       ^ (rB & 7)) * 16));
    const uint32_t boff1 = (uint32_t)(rB * 128 + (((4 | ks) ^ (rB & 7)) * 16));

    f32x4 acc[4][4] = {};
    const int NT = K >> 6;

    // ---- prologue: stage tile 0 into slot 0, full drain ----
    STAGEI(0, 0, 0); STAGEI(1, 0, 0); STAGEI(2, 0, 0);
    STAGEI(3, 0, 0); STAGEI(4, 0, 0); STAGEI(5, 0, 0);
    __syncthreads();

    for (int t = 0; t < NT; ++t) {
        const int cur = t & 1, nxt = cur ^ 1;
        const uint32_t acur = (uint32_t)cur * 32768u;
        const uint32_t bcur = 65536u + (uint32_t)cur * 16384u;
        const bool pf = (t + 1 < NT);
        const int ktn = (t + 1) << 6;

        bf16x8 a0, a1, a2, a3, b0, b1, b2, b3;

        // ---- phase 0: kk=0, m rows 0-1 ; issue first half of next-tile stage ----
        a0 = RD_A(0, aoff0); a1 = RD_A(1, aoff0);
        b0 = RD_B(0, boff0); b1 = RD_B(1, boff0); b2 = RD_B(2, boff0); b3 = RD_B(3, boff0);
        if (pf) { STAGEI(0, ktn, nxt); STAGEI(1, ktn, nxt); STAGEI(2, ktn, nxt); }
        BAR(); WAIT_LGKM0();
        __builtin_amdgcn_s_setprio(1);
        MFMA(acc[0][0], a0, b0); MFMA(acc[0][1], a0, b1); MFMA(acc[0][2], a0, b2); MFMA(acc[0][3], a0, b3);
        MFMA(acc[1][0], a1, b0); MFMA(acc[1][1], a1, b1); MFMA(acc[1][2], a1, b2); MFMA(acc[1][3], a1, b3);
        __builtin_amdgcn_s_setprio(0);
        BAR();

        // ---- phase 1: kk=0, m rows 2-3 ; issue second half of next-tile stage ----
        a2 = RD_A(2, aoff0); a3 = RD_A(3, aoff0);
        if (pf) { STAGEI(3, ktn, nxt); STAGEI(4, ktn, nxt); STAGEI(5, ktn, nxt); }
        BAR(); WAIT_LGKM0();
        __builtin_amdgcn_s_setprio(1);
        MFMA(acc[2][0], a2, b0); MFMA(acc[2][1], a2, b1); MFMA(acc[2][2], a2, b2); MFMA(acc[2][3], a2, b3);
        MFMA(acc[3][0], a3, b0); MFMA(acc[3][1], a3, b1); MFMA(acc[3][2], a3, b2); MFMA(acc[3][3], a3, b3);
        __builtin_amdgcn_s_setprio(0);
        BAR();

        // ---- phase 2: kk=1, m rows 0-1 ----
        a0 = RD_A(0, aoff1); a1 = RD_A(1, aoff1);
        b0 = RD_B(0, boff1); b1 = RD_B(1, boff1); b2 = RD_B(2, boff1); b3 = RD_B(3, boff1);
        BAR(); WAIT_LGKM0();
        __builtin_amdgcn_s_setprio(1);
        MFMA(acc[0][0], a0, b0); MFMA(acc[0][1], a0, b1); MFMA(acc[0][2], a0, b2); MFMA(acc[0][3], a0, b3);
        MFMA(acc[1][0], a1, b0); MFMA(acc[1][1], a1, b1); MFMA(acc[1][2], a1, b2); MFMA(acc[1][3], a1, b3);
        __builtin_amdgcn_s_setprio(0);
        BAR();

        // ---- phase 3: kk=1, m rows 2-3 ; full drain + barrier at buffer swap ----
        a2 = RD_A(2, aoff1); a3 = RD_A(3, aoff1);
        BAR(); WAIT_LGKM0();
        __builtin_amdgcn_s_setprio(1);
        MFMA(acc[2][0], a2, b0); MFMA(acc[2][1], a2, b1); MFMA(acc[2][2], a2, b2); MFMA(acc[2][3], a2, b3);
        MFMA(acc[3][0], a3, b0); MFMA(acc[3][1], a3, b1); MFMA(acc[3][2], a3, b2); MFMA(acc[3][3], a3, b3);
        __builtin_amdgcn_s_setprio(0);
        __syncthreads();   // waits vmcnt(0) lgkmcnt(0) + barrier, fully modeled
    }

    // ---- epilogue: bias + relu + bf16 store ----
    const int col0 = bn * 128 + wc * 64 + (lane & 15);
    const int row0 = bm * 256 + wr * 64 + ((lane >> 4) << 2);
    #pragma unroll
    for (int n = 0; n < 4; ++n) {
        const int col = col0 + n * 16;
        const float bv = bias[col];
        #pragma unroll
        for (int m = 0; m < 4; ++m) {
            #pragma unroll
            for (int j = 0; j < 4; ++j) {
                float v = acc[m][n][j] + bv;
                v = v > 0.0f ? v : 0.0f;
                C[(size_t)(row0 + m * 16 + j) * HID + col] = f2bf(v);
            }
        }
    }
}

// ---------------- head: out[b,o] = sum_k h[b,k]*hw[task[b],o,k] + hb[task[b],o]
// one wave per batch row; vectorized bf16x8 h loads, fp32 head weights
__global__ __launch_bounds__(256) void bl_head(
    const unsigned short* __restrict__ h,   // [4096][2048] bf16
    const float* __restrict__ hw,           // [10][10][2048] f32
    const float* __restrict__ hb,           // [10][10] f32
    const int* __restrict__ task,           // [4096] i32
    float* __restrict__ out)                // [4096][10] f32
{
    const int wave = threadIdx.x >> 6, lane = threadIdx.x & 63;
    const int b = blockIdx.x * 4 + wave;
    const int t = task[b];
    const float* w = hw + (size_t)t * OUT_DIM * HID;
    const unsigned short* hr = h + (size_t)b * HID;

    float acc[OUT_DIM];
    #pragma unroll
    for (int o = 0; o < OUT_DIM; ++o) acc[o] = 0.0f;

    #pragma unroll
    for (int i = 0; i < HID / 512; ++i) {           // 4 iters, 8 elems/lane each
        const int k0 = (i * 64 + lane) * 8;
        const bf16x8 hv8 = *(const bf16x8*)(hr + k0);
        float hf[8];
        #pragma unroll
        for (int j = 0; j < 8; ++j) hf[j] = (float)hv8[j];
        #pragma unroll
        for (int o = 0; o < OUT_DIM; ++o) {
            const float4 w0 = *(const float4*)(w + (size_t)o * HID + k0);
            const float4 w1 = *(const float4*)(w + (size_t)o * HID + k0 + 4);
            acc[o] += hf[0]*w0.x + hf[1]*w0.y + hf[2]*w0.z + hf[3]*w0.w
                    + hf[4]*w1.x + hf[5]*w1.y + hf[6]*w1.z + hf[7]*w1.w;
        }
    }
    #pragma unroll
    for (int o = 0; o < OUT_DIM; ++o) {
        float v = acc[o];
        #pragma unroll
        for (int s = 32; s > 0; s >>= 1) v += __shfl_down(v, s, 64);
        if (lane == 0) out[(size_t)b * OUT_DIM + o] = v + hb[t * OUT_DIM + o];
    }
}

// ---------------- launch ----------------

extern "C" void kernel_launch(void* const* d_in, const int* in_sizes, int n_in,
                              void* d_out, int out_size, void* d_ws, size_t ws_size,
                              hipStream_t stream)
{
    const float* x      = (const float*)d_in[0];
    const float* mu_w0  = (const float*)d_in[1];
    const float* ls_w0  = (const float*)d_in[2];
    const float* mu_b0  = (const float*)d_in[3];
    const float* ls_b0  = (const float*)d_in[4];
    const float* mu_w   = (const float*)d_in[5];
    const float* ls_w   = (const float*)d_in[6];
    const float* mu_b   = (const float*)d_in[7];
    const float* ls_b   = (const float*)d_in[8];
    const float* mu_hw  = (const float*)d_in[9];
    const float* ls_hw  = (const float*)d_in[10];
    const float* mu_hb  = (const float*)d_in[11];
    const float* ls_hb  = (const float*)d_in[12];
    const float* eps_w0 = (const float*)d_in[13];
    const float* eps_b0 = (const float*)d_in[14];
    const float* eps_w  = (const float*)d_in[15];
    const float* eps_b  = (const float*)d_in[16];
    const float* eps_hw = (const float*)d_in[17];
    const float* eps_hb = (const float*)d_in[18];
    const int*   task   = (const int*)d_in[19];

    uint8_t* ws = (uint8_t*)d_ws;
    constexpr size_t X_OFF  = 0;
    constexpr size_t W0_OFF = X_OFF  + (size_t)BATCH * IN_DIM * 2;       // x bf16
    constexpr size_t W_OFF  = W0_OFF + (size_t)HID * IN_DIM * 2;         // w0 bf16
    constexpr size_t H0_OFF = W_OFF  + (size_t)3 * HID * HID * 2;        // w1..3 bf16
    constexpr size_t H1_OFF = H0_OFF + (size_t)BATCH * HID * 2;          // h ping
    constexpr size_t B_OFF  = H1_OFF + (size_t)BATCH * HID * 2;          // h pong
    constexpr size_t HW_OFF = B_OFF  + (size_t)4 * HID * 4;              // biases f32
    constexpr size_t HB_OFF = HW_OFF + (size_t)NTASKS * OUT_DIM * HID * 4;

    unsigned short* xbf = (unsigned short*)(ws + X_OFF);
    unsigned short* w0b = (unsigned short*)(ws + W0_OFF);
    unsigned short* wb  = (unsigned short*)(ws + W_OFF);
    unsigned short* h0  = (unsigned short*)(ws + H0_OFF);
    unsigned short* h1  = (unsigned short*)(ws + H1_OFF);
    float* ball = (float*)(ws + B_OFF);
    float* hwf  = (float*)(ws + HW_OFF);
    float* hbf  = (float*)(ws + HB_OFF);

    // exact grids: n4 / 1024 (all divisible)
    bl_cvt<<<BATCH * IN_DIM / 4096, 256, 0, stream>>>((const float4*)x, (ushort4*)xbf);
    bl_transform<<<HID * IN_DIM / 4096, 256, 0, stream>>>(
        (const float4*)mu_w0, (const float4*)ls_w0, (const float4*)eps_w0, (ushort4*)w0b);
    bl_transform<<<3 * HID * HID / 4096, 256, 0, stream>>>(
        (const float4*)mu_w, (const float4*)ls_w, (const float4*)eps_w, (ushort4*)wb);
    bl_small<<<512, 256, 0, stream>>>(mu_b0, ls_b0, eps_b0, mu_b, ls_b, eps_b,
                                      mu_hw, ls_hw, eps_hw, mu_hb, ls_hb, eps_hb,
                                      ball, hwf, hbf);

    bl_gemm<<<256, 512, 0, stream>>>(xbf, w0b, ball,             h0, IN_DIM);
    bl_gemm<<<256, 512, 0, stream>>>(h0, wb,                     ball + HID,   h1, HID);
    bl_gemm<<<256, 512, 0, stream>>>(h1, wb + (size_t)HID*HID,   ball + 2*HID, h0, HID);
    bl_gemm<<<256, 512, 0, stream>>>(h0, wb + (size_t)2*HID*HID, ball + 3*HID, h1, HID);

    bl_head<<<BATCH / 4, 256, 0, stream>>>(h1, hwf, hbf, task, (float*)d_out);
}

// Round 5
// 212.263 us; speedup vs baseline: 1.0080x; 1.0080x over previous
//
#include <hip/hip_runtime.h>
#include <cstdint>

#define BATCH 4096
#define IN_DIM 1024
#define HID 2048
#define OUT_DIM 10
#define NTASKS 10

typedef __bf16 bf16x8 __attribute__((ext_vector_type(8)));
typedef float f32x4 __attribute__((ext_vector_type(4)));
typedef __attribute__((address_space(3))) uint8_t lds_u8;
typedef const __attribute__((address_space(1))) uint8_t glb_u8;

__device__ __forceinline__ unsigned short f2bf(float f) {
    uint32_t u = __builtin_bit_cast(uint32_t, f);
    u += 0x7fffu + ((u >> 16) & 1u);   // round-to-nearest-even
    return (unsigned short)(u >> 16);
}
__device__ __forceinline__ float bf2f(unsigned short h) {
    uint32_t u = ((uint32_t)h) << 16;
    return __builtin_bit_cast(float, u);
}
__device__ __forceinline__ uint32_t pk(float a, float b) {
    return (uint32_t)f2bf(a) | ((uint32_t)f2bf(b) << 16);
}

// ---------------- transform kernels ----------------
// Round-4 lesson: the scheduler sinks loads to their uses (VGPR_Count=28,
// ~3 loads in flight -> latency-chained, 1.8 TB/s HBM). Fix: issue ALL 12
// dwordx4 loads, then sched_barrier(0) so nothing crosses -> 12 KB in
// flight per wave, forced by construction. Outputs paired into 16B uint4.
// Each block: 1024 float4 in, 512 uint4 out. Grids sized exactly.

__global__ __launch_bounds__(256) void bl_transform(
    const float4* __restrict__ mu, const float4* __restrict__ ls,
    const float4* __restrict__ eps, uint4* __restrict__ out)
{
    const int t  = threadIdx.x;
    const int fb = blockIdx.x * 1024;
    const int ia = fb + 2 * t;          // adjacent pair (32B) in first half
    const int ib = fb + 512 + 2 * t;    // adjacent pair in second half
    const float4 m0 = mu[ia], m1 = mu[ia + 1], m2 = mu[ib], m3 = mu[ib + 1];
    const float4 l0 = ls[ia], l1 = ls[ia + 1], l2 = ls[ib], l3 = ls[ib + 1];
    const float4 e0 = eps[ia], e1 = eps[ia + 1], e2 = eps[ib], e3 = eps[ib + 1];
    __builtin_amdgcn_sched_barrier(0);  // keep all 12 loads issued & in flight
    uint4 o0, o1;
    o0.x = pk(m0.x + __expf(l0.x) * e0.x, m0.y + __expf(l0.y) * e0.y);
    o0.y = pk(m0.z + __expf(l0.z) * e0.z, m0.w + __expf(l0.w) * e0.w);
    o0.z = pk(m1.x + __expf(l1.x) * e1.x, m1.y + __expf(l1.y) * e1.y);
    o0.w = pk(m1.z + __expf(l1.z) * e1.z, m1.w + __expf(l1.w) * e1.w);
    o1.x = pk(m2.x + __expf(l2.x) * e2.x, m2.y + __expf(l2.y) * e2.y);
    o1.y = pk(m2.z + __expf(l2.z) * e2.z, m2.w + __expf(l2.w) * e2.w);
    o1.z = pk(m3.x + __expf(l3.x) * e3.x, m3.y + __expf(l3.y) * e3.y);
    o1.w = pk(m3.z + __expf(l3.z) * e3.z, m3.w + __expf(l3.w) * e3.w);
    out[blockIdx.x * 512 + t]       = o0;
    out[blockIdx.x * 512 + 256 + t] = o1;
}

__global__ __launch_bounds__(256) void bl_cvt(
    const float4* __restrict__ in, uint4* __restrict__ out)
{
    const int t  = threadIdx.x;
    const int fb = blockIdx.x * 1024;
    const int ia = fb + 2 * t;
    const int ib = fb + 512 + 2 * t;
    const float4 v0 = in[ia], v1 = in[ia + 1], v2 = in[ib], v3 = in[ib + 1];
    __builtin_amdgcn_sched_barrier(0);
    uint4 o0, o1;
    o0.x = pk(v0.x, v0.y); o0.y = pk(v0.z, v0.w);
    o0.z = pk(v1.x, v1.y); o0.w = pk(v1.z, v1.w);
    o1.x = pk(v2.x, v2.y); o1.y = pk(v2.z, v2.w);
    o1.z = pk(v3.x, v3.y); o1.w = pk(v3.z, v3.w);
    out[blockIdx.x * 512 + t]       = o0;
    out[blockIdx.x * 512 + 256 + t] = o1;
}

__global__ __launch_bounds__(256) void bl_small(
    const float* __restrict__ mu_b0, const float* __restrict__ ls_b0, const float* __restrict__ eps_b0,
    const float* __restrict__ mu_b,  const float* __restrict__ ls_b,  const float* __restrict__ eps_b,
    const float* __restrict__ mu_hw, const float* __restrict__ ls_hw, const float* __restrict__ eps_hw,
    const float* __restrict__ mu_hb, const float* __restrict__ ls_hb, const float* __restrict__ eps_hb,
    float* __restrict__ b_all, float* __restrict__ hw, float* __restrict__ hb)
{
    const int total = HID + 3*HID + NTASKS*OUT_DIM*HID + NTASKS*OUT_DIM;
    int i = blockIdx.x * blockDim.x + threadIdx.x;
    const int stride = gridDim.x * blockDim.x;
    for (; i < total; i += stride) {
        if (i < HID) {
            b_all[i] = mu_b0[i] + __expf(ls_b0[i]) * eps_b0[i];
        } else if (i < 4*HID) {
            const int j = i - HID;
            b_all[HID + j] = mu_b[j] + __expf(ls_b[j]) * eps_b[j];
        } else if (i < 4*HID + NTASKS*OUT_DIM*HID) {
            const int j = i - 4*HID;
            hw[j] = mu_hw[j] + __expf(ls_hw[j]) * eps_hw[j];
        } else {
            const int j = i - (4*HID + NTASKS*OUT_DIM*HID);
            hb[j] = mu_hb[j] + __expf(ls_hb[j]) * eps_hb[j];
        }
    }
}

// ---------------- GEMM: C[4096,2048] = relu(A[4096,K] @ B[2048,K]^T + bias)
// BM=256 BN=128 BK=64, 8 waves (4M x 2N, 64x64 each), double-buffered LDS (96KB),
// 4 phases per K-tile. Barriers are inline-asm s_barrier WITH "memory" clobber
// (the s_barrier builtin is IntrNoMem -> round-2 replay race). Full-drain points
// use __syncthreads(). Both next-tile stage halves issue in phases 0/1 so the
// end-of-tile vmcnt(0) drain has ~3 phases of MFMA cover.
#define BAR()        asm volatile("s_barrier" ::: "memory")
#define WAIT_LGKM0() do { asm volatile("s_waitcnt lgkmcnt(0)" ::: "memory"); __builtin_amdgcn_sched_barrier(0); } while (0)
#define RD_A(m, o)   (*(const bf16x8*)(ldsb + acur + (o) + (m)*2048))
#define RD_B(n, o)   (*(const bf16x8*)(ldsb + bcur + (o) + (n)*2048))
#define MFMA(d, va, vb) d = __builtin_amdgcn_mfma_f32_16x16x32_bf16(va, vb, d, 0, 0, 0)
#define STAGEI(i, kel, sl) \
    __builtin_amdgcn_global_load_lds((glb_u8*)(gsrc[i] + (kel)), \
        (lds_u8*)(ldsb + ldst[i] + (uint32_t)(sl) * smul[i]), 16, 0, 0)

__global__ __launch_bounds__(512, 2) void bl_gemm(
    const unsigned short* __restrict__ A,   // [4096][K] bf16
    const unsigned short* __restrict__ B,   // [2048][K] bf16
    const float* __restrict__ bias,         // [2048]
    unsigned short* __restrict__ C,         // [4096][2048] bf16
    int K)
{
    // LDS: A slots @0 and @32768 bytes (256x64 bf16 each); B slots @65536, @81920 (128x64)
    __shared__ unsigned short lds[49152];   // 96 KB
    uint8_t* ldsb = (uint8_t*)lds;

    const int tid  = threadIdx.x;
    const int wave = tid >> 6;
    const int lane = tid & 63;
    // bijective XCD swizzle: nwg=256, 8 XCDs, 32 contiguous wgs per XCD
    const int swz = ((blockIdx.x & 7) << 5) | (blockIdx.x >> 3);
    const int bm = swz >> 4;        // 0..15  (M tiles of 256)
    const int bn = swz & 15;        // 0..15  (N tiles of 128)
    const int wr = wave >> 1;       // 0..3 -> m offset wr*64
    const int wc = wave & 1;        // 0..1 -> n offset wc*64

    // ---- staging setup: 48 chunks/tile (32 A + 16 B), 6 per wave ----
    // chunk c covers LDS linear bytes [c*1024, +1024) of its region = rows c*8..c*8+7.
    // lane l -> row = c*8 + (l>>3), 16B slot (l&7); swizzled source slot = (l&7)^(l>>3).
    const int lr8 = lane >> 3;
    const int ss  = (lane & 7) ^ lr8;
    const unsigned short* gsrc[6];
    uint32_t ldst[6], smul[6];
    #pragma unroll
    for (int i = 0; i < 6; ++i) {
        const int c = wave * 6 + i;
        if (c < 32) {
            gsrc[i] = A + (size_t)(bm * 256 + c * 8 + lr8) * K + ss * 8;
            ldst[i] = (uint32_t)c * 1024u;
            smul[i] = 32768u;
        } else {
            gsrc[i] = B + (size_t)(bn * 128 + (c - 32) * 8 + lr8) * K + ss * 8;
            ldst[i] = 65536u + (uint32_t)(c - 32) * 1024u;
            smul[i] = 16384u;
        }
    }

    // ---- fragment-read offsets (row stride 128B, slot ^= row&7 swizzle) ----
    const int rA = wr * 64 + (lane & 15);
    const int rB = wc * 64 + (lane & 15);
    const int ks = lane >> 4;                    // 16B slot within 32-wide k-block
    const uint32_t aoff0 = (uint32_t)(rA * 128 + ((ks       ^ (rA & 7)) * 16));
    const uint32_t aoff1 = (uint32_t)(rA * 128 + (((4 | ks) ^ (rA & 7)) * 16));
    const uint32_t boff0 = (uint32_t)(rB * 128 + ((ks       ^ (rB & 7)) * 16));
    const uint32_t boff1 = (uint32_t)(rB * 128 + (((4 | ks) ^ (rB & 7)) * 16));

    f32x4 acc[4][4] = {};
    const int NT = K >> 6;

    // ---- prologue: stage tile 0 into slot 0, full drain ----
    STAGEI(0, 0, 0); STAGEI(1, 0, 0); STAGEI(2, 0, 0);
    STAGEI(3, 0, 0); STAGEI(4, 0, 0); STAGEI(5, 0, 0);
    __syncthreads();

    for (int t = 0; t < NT; ++t) {
        const int cur = t & 1, nxt = cur ^ 1;
        const uint32_t acur = (uint32_t)cur * 32768u;
        const uint32_t bcur = 65536u + (uint32_t)cur * 16384u;
        const bool pf = (t + 1 < NT);
        const int ktn = (t + 1) << 6;

        bf16x8 a0, a1, a2, a3, b0, b1, b2, b3;

        // ---- phase 0: kk=0, m rows 0-1 ; issue first half of next-tile stage ----
        a0 = RD_A(0, aoff0); a1 = RD_A(1, aoff0);
        b0 = RD_B(0, boff0); b1 = RD_B(1, boff0); b2 = RD_B(2, boff0); b3 = RD_B(3, boff0);
        if (pf) { STAGEI(0, ktn, nxt); STAGEI(1, ktn, nxt); STAGEI(2, ktn, nxt); }
        BAR(); WAIT_LGKM0();
        __builtin_amdgcn_s_setprio(1);
        MFMA(acc[0][0], a0, b0); MFMA(acc[0][1], a0, b1); MFMA(acc[0][2], a0, b2); MFMA(acc[0][3], a0, b3);
        MFMA(acc[1][0], a1, b0); MFMA(acc[1][1], a1, b1); MFMA(acc[1][2], a1, b2); MFMA(acc[1][3], a1, b3);
        __builtin_amdgcn_s_setprio(0);
        BAR();

        // ---- phase 1: kk=0, m rows 2-3 ; issue second half of next-tile stage ----
        a2 = RD_A(2, aoff0); a3 = RD_A(3, aoff0);
        if (pf) { STAGEI(3, ktn, nxt); STAGEI(4, ktn, nxt); STAGEI(5, ktn, nxt); }
        BAR(); WAIT_LGKM0();
        __builtin_amdgcn_s_setprio(1);
        MFMA(acc[2][0], a2, b0); MFMA(acc[2][1], a2, b1); MFMA(acc[2][2], a2, b2); MFMA(acc[2][3], a2, b3);
        MFMA(acc[3][0], a3, b0); MFMA(acc[3][1], a3, b1); MFMA(acc[3][2], a3, b2); MFMA(acc[3][3], a3, b3);
        __builtin_amdgcn_s_setprio(0);
        BAR();

        // ---- phase 2: kk=1, m rows 0-1 ----
        a0 = RD_A(0, aoff1); a1 = RD_A(1, aoff1);
        b0 = RD_B(0, boff1); b1 = RD_B(1, boff1); b2 = RD_B(2, boff1); b3 = RD_B(3, boff1);
        BAR(); WAIT_LGKM0();
        __builtin_amdgcn_s_setprio(1);
        MFMA(acc[0][0], a0, b0); MFMA(acc[0][1], a0, b1); MFMA(acc[0][2], a0, b2); MFMA(acc[0][3], a0, b3);
        MFMA(acc[1][0], a1, b0); MFMA(acc[1][1], a1, b1); MFMA(acc[1][2], a1, b2); MFMA(acc[1][3], a1, b3);
        __builtin_amdgcn_s_setprio(0);
        BAR();

        // ---- phase 3: kk=1, m rows 2-3 ; full drain + barrier at buffer swap ----
        a2 = RD_A(2, aoff1); a3 = RD_A(3, aoff1);
        BAR(); WAIT_LGKM0();
        __builtin_amdgcn_s_setprio(1);
        MFMA(acc[2][0], a2, b0); MFMA(acc[2][1], a2, b1); MFMA(acc[2][2], a2, b2); MFMA(acc[2][3], a2, b3);
        MFMA(acc[3][0], a3, b0); MFMA(acc[3][1], a3, b1); MFMA(acc[3][2], a3, b2); MFMA(acc[3][3], a3, b3);
        __builtin_amdgcn_s_setprio(0);
        __syncthreads();   // waits vmcnt(0) lgkmcnt(0) + barrier, fully modeled
    }

    // ---- epilogue: bias + relu + bf16 store ----
    const int col0 = bn * 128 + wc * 64 + (lane & 15);
    const int row0 = bm * 256 + wr * 64 + ((lane >> 4) << 2);
    #pragma unroll
    for (int n = 0; n < 4; ++n) {
        const int col = col0 + n * 16;
        const float bv = bias[col];
        #pragma unroll
        for (int m = 0; m < 4; ++m) {
            #pragma unroll
            for (int j = 0; j < 4; ++j) {
                float v = acc[m][n][j] + bv;
                v = v > 0.0f ? v : 0.0f;
                C[(size_t)(row0 + m * 16 + j) * HID + col] = f2bf(v);
            }
        }
    }
}

// ---------------- head: out[b,o] = sum_k h[b,k]*hw[task[b],o,k] + hb[task[b],o]
// one wave per batch row; vectorized bf16x8 h loads, fp32 head weights
__global__ __launch_bounds__(256) void bl_head(
    const unsigned short* __restrict__ h,   // [4096][2048] bf16
    const float* __restrict__ hw,           // [10][10][2048] f32
    const float* __restrict__ hb,           // [10][10] f32
    const int* __restrict__ task,           // [4096] i32
    float* __restrict__ out)                // [4096][10] f32
{
    const int wave = threadIdx.x >> 6, lane = threadIdx.x & 63;
    const int b = blockIdx.x * 4 + wave;
    const int t = task[b];
    const float* w = hw + (size_t)t * OUT_DIM * HID;
    const unsigned short* hr = h + (size_t)b * HID;

    float acc[OUT_DIM];
    #pragma unroll
    for (int o = 0; o < OUT_DIM; ++o) acc[o] = 0.0f;

    #pragma unroll
    for (int i = 0; i < HID / 512; ++i) {           // 4 iters, 8 elems/lane each
        const int k0 = (i * 64 + lane) * 8;
        const bf16x8 hv8 = *(const bf16x8*)(hr + k0);
        float hf[8];
        #pragma unroll
        for (int j = 0; j < 8; ++j) hf[j] = (float)hv8[j];
        #pragma unroll
        for (int o = 0; o < OUT_DIM; ++o) {
            const float4 w0 = *(const float4*)(w + (size_t)o * HID + k0);
            const float4 w1 = *(const float4*)(w + (size_t)o * HID + k0 + 4);
            acc[o] += hf[0]*w0.x + hf[1]*w0.y + hf[2]*w0.z + hf[3]*w0.w
                    + hf[4]*w1.x + hf[5]*w1.y + hf[6]*w1.z + hf[7]*w1.w;
        }
    }
    #pragma unroll
    for (int o = 0; o < OUT_DIM; ++o) {
        float v = acc[o];
        #pragma unroll
        for (int s = 32; s > 0; s >>= 1) v += __shfl_down(v, s, 64);
        if (lane == 0) out[(size_t)b * OUT_DIM + o] = v + hb[t * OUT_DIM + o];
    }
}

// ---------------- launch ----------------

extern "C" void kernel_launch(void* const* d_in, const int* in_sizes, int n_in,
                              void* d_out, int out_size, void* d_ws, size_t ws_size,
                              hipStream_t stream)
{
    const float* x      = (const float*)d_in[0];
    const float* mu_w0  = (const float*)d_in[1];
    const float* ls_w0  = (const float*)d_in[2];
    const float* mu_b0  = (const float*)d_in[3];
    const float* ls_b0  = (const float*)d_in[4];
    const float* mu_w   = (const float*)d_in[5];
    const float* ls_w   = (const float*)d_in[6];
    const float* mu_b   = (const float*)d_in[7];
    const float* ls_b   = (const float*)d_in[8];
    const float* mu_hw  = (const float*)d_in[9];
    const float* ls_hw  = (const float*)d_in[10];
    const float* mu_hb  = (const float*)d_in[11];
    const float* ls_hb  = (const float*)d_in[12];
    const float* eps_w0 = (const float*)d_in[13];
    const float* eps_b0 = (const float*)d_in[14];
    const float* eps_w  = (const float*)d_in[15];
    const float* eps_b  = (const float*)d_in[16];
    const float* eps_hw = (const float*)d_in[17];
    const float* eps_hb = (const float*)d_in[18];
    const int*   task   = (const int*)d_in[19];

    uint8_t* ws = (uint8_t*)d_ws;
    constexpr size_t X_OFF  = 0;
    constexpr size_t W0_OFF = X_OFF  + (size_t)BATCH * IN_DIM * 2;       // x bf16
    constexpr size_t W_OFF  = W0_OFF + (size_t)HID * IN_DIM * 2;         // w0 bf16
    constexpr size_t H0_OFF = W_OFF  + (size_t)3 * HID * HID * 2;        // w1..3 bf16
    constexpr size_t H1_OFF = H0_OFF + (size_t)BATCH * HID * 2;          // h ping
    constexpr size_t B_OFF  = H1_OFF + (size_t)BATCH * HID * 2;          // h pong
    constexpr size_t HW_OFF = B_OFF  + (size_t)4 * HID * 4;              // biases f32
    constexpr size_t HB_OFF = HW_OFF + (size_t)NTASKS * OUT_DIM * HID * 4;

    unsigned short* xbf = (unsigned short*)(ws + X_OFF);
    unsigned short* w0b = (unsigned short*)(ws + W0_OFF);
    unsigned short* wb  = (unsigned short*)(ws + W_OFF);
    unsigned short* h0  = (unsigned short*)(ws + H0_OFF);
    unsigned short* h1  = (unsigned short*)(ws + H1_OFF);
    float* ball = (float*)(ws + B_OFF);
    float* hwf  = (float*)(ws + HW_OFF);
    float* hbf  = (float*)(ws + HB_OFF);

    // exact grids: 1024 float4 per block
    bl_cvt<<<BATCH * IN_DIM / 4096, 256, 0, stream>>>((const float4*)x, (uint4*)xbf);
    bl_transform<<<HID * IN_DIM / 4096, 256, 0, stream>>>(
        (const float4*)mu_w0, (const float4*)ls_w0, (const float4*)eps_w0, (uint4*)w0b);
    bl_transform<<<3 * HID * HID / 4096, 256, 0, stream>>>(
        (const float4*)mu_w, (const float4*)ls_w, (const float4*)eps_w, (uint4*)wb);
    bl_small<<<512, 256, 0, stream>>>(mu_b0, ls_b0, eps_b0, mu_b, ls_b, eps_b,
                                      mu_hw, ls_hw, eps_hw, mu_hb, ls_hb, eps_hb,
                                      ball, hwf, hbf);

    bl_gemm<<<256, 512, 0, stream>>>(xbf, w0b, ball,             h0, IN_DIM);
    bl_gemm<<<256, 512, 0, stream>>>(h0, wb,                     ball + HID,   h1, HID);
    bl_gemm<<<256, 512, 0, stream>>>(h1, wb + (size_t)HID*HID,   ball + 2*HID, h0, HID);
    bl_gemm<<<256, 512, 0, stream>>>(h0, wb + (size_t)2*HID*HID, ball + 3*HID, h1, HID);

    bl_head<<<BATCH / 4, 256, 0, stream>>>(h1, hwf, hbf, task, (float*)d_out);
}

// Round 6
// 198.444 us; speedup vs baseline: 1.0781x; 1.0696x over previous
//
#include <hip/hip_runtime.h>
#include <cstdint>

#define BATCH 4096
#define IN_DIM 1024
#define HID 2048
#define OUT_DIM 10
#define NTASKS 10

typedef __bf16 bf16x8 __attribute__((ext_vector_type(8)));
typedef float f32x4 __attribute__((ext_vector_type(4)));
typedef __attribute__((address_space(3))) uint8_t lds_u8;
typedef const __attribute__((address_space(1))) uint8_t glb_u8;

__device__ __forceinline__ unsigned short f2bf(float f) {
    uint32_t u = __builtin_bit_cast(uint32_t, f);
    u += 0x7fffu + ((u >> 16) & 1u);   // round-to-nearest-even
    return (unsigned short)(u >> 16);
}
__device__ __forceinline__ float bf2f(unsigned short h) {
    uint32_t u = ((uint32_t)h) << 16;
    return __builtin_bit_cast(float, u);
}
__device__ __forceinline__ uint32_t pk(float a, float b) {
    return (uint32_t)f2bf(a) | ((uint32_t)f2bf(b) << 16);
}

// ---------------- standalone transforms (pre-GEMM0 inputs only) ----------------

__global__ __launch_bounds__(256) void bl_transform(
    const float4* __restrict__ mu, const float4* __restrict__ ls,
    const float4* __restrict__ eps, uint4* __restrict__ out)
{
    const int t  = threadIdx.x;
    const int fb = blockIdx.x * 1024;
    const int ia = fb + 2 * t;
    const int ib = fb + 512 + 2 * t;
    const float4 m0 = mu[ia], m1 = mu[ia + 1], m2 = mu[ib], m3 = mu[ib + 1];
    const float4 l0 = ls[ia], l1 = ls[ia + 1], l2 = ls[ib], l3 = ls[ib + 1];
    const float4 e0 = eps[ia], e1 = eps[ia + 1], e2 = eps[ib], e3 = eps[ib + 1];
    uint4 o0, o1;
    o0.x = pk(m0.x + __expf(l0.x) * e0.x, m0.y + __expf(l0.y) * e0.y);
    o0.y = pk(m0.z + __expf(l0.z) * e0.z, m0.w + __expf(l0.w) * e0.w);
    o0.z = pk(m1.x + __expf(l1.x) * e1.x, m1.y + __expf(l1.y) * e1.y);
    o0.w = pk(m1.z + __expf(l1.z) * e1.z, m1.w + __expf(l1.w) * e1.w);
    o1.x = pk(m2.x + __expf(l2.x) * e2.x, m2.y + __expf(l2.y) * e2.y);
    o1.y = pk(m2.z + __expf(l2.z) * e2.z, m2.w + __expf(l2.w) * e2.w);
    o1.z = pk(m3.x + __expf(l3.x) * e3.x, m3.y + __expf(l3.y) * e3.y);
    o1.w = pk(m3.z + __expf(l3.z) * e3.z, m3.w + __expf(l3.w) * e3.w);
    out[blockIdx.x * 512 + t]       = o0;
    out[blockIdx.x * 512 + 256 + t] = o1;
}

__global__ __launch_bounds__(256) void bl_cvt(
    const float4* __restrict__ in, uint4* __restrict__ out)
{
    const int t  = threadIdx.x;
    const int fb = blockIdx.x * 1024;
    const int ia = fb + 2 * t;
    const int ib = fb + 512 + 2 * t;
    const float4 v0 = in[ia], v1 = in[ia + 1], v2 = in[ib], v3 = in[ib + 1];
    uint4 o0, o1;
    o0.x = pk(v0.x, v0.y); o0.y = pk(v0.z, v0.w);
    o0.z = pk(v1.x, v1.y); o0.w = pk(v1.z, v1.w);
    o1.x = pk(v2.x, v2.y); o1.y = pk(v2.z, v2.w);
    o1.z = pk(v3.x, v3.y); o1.w = pk(v3.z, v3.w);
    out[blockIdx.x * 512 + t]       = o0;
    out[blockIdx.x * 512 + 256 + t] = o1;
}

// biases only: b0 (HID), b1..3 (3*HID), hb (100)
__global__ __launch_bounds__(256) void bl_small(
    const float* __restrict__ mu_b0, const float* __restrict__ ls_b0, const float* __restrict__ eps_b0,
    const float* __restrict__ mu_b,  const float* __restrict__ ls_b,  const float* __restrict__ eps_b,
    const float* __restrict__ mu_hb, const float* __restrict__ ls_hb, const float* __restrict__ eps_hb,
    float* __restrict__ b_all, float* __restrict__ hb)
{
    const int total = 4 * HID + NTASKS * OUT_DIM;
    const int i = blockIdx.x * blockDim.x + threadIdx.x;
    if (i >= total) return;
    if (i < HID) {
        b_all[i] = mu_b0[i] + __expf(ls_b0[i]) * eps_b0[i];
    } else if (i < 4 * HID) {
        const int j = i - HID;
        b_all[HID + j] = mu_b[j] + __expf(ls_b[j]) * eps_b[j];
    } else {
        const int j = i - 4 * HID;
        hb[j] = mu_hb[j] + __expf(ls_hb[j]) * eps_hb[j];
    }
}

// ---------------- fused GEMM + next-layer weight transform ----------------
// C[4096,2048] = relu(A[4096,K] @ B[2048,K]^T + bias), bf16, fp32 acc.
// Waves 0-7 (512 thr): BM=256 BN=128 BK=64 GEMM, dbuf LDS 96KB, 4 phases/K-tile.
// Waves 8-9 (128 thr): elementwise transform of the NEXT layer's weights
// (mu + exp(ls)*eps), pipelined one gap ahead, executing the IDENTICAL barrier
// sequence per iteration: 7x BAR() + 1x __syncthreads(). The transform is pure
// HBM traffic and rides in the GEMM's memory shadow (GEMM is MFMA/LDS-bound).
// TMODE 0: bf16 output (hidden weights, UPG units/gap). TMODE 1: f32 output
// (head weights, 200 units/block over first 2 gaps).
#define BAR()        asm volatile("s_barrier" ::: "memory")
#define WAIT_LGKM0() do { asm volatile("s_waitcnt lgkmcnt(0)" ::: "memory"); __builtin_amdgcn_sched_barrier(0); } while (0)
#define RD_A(m, o)   (*(const bf16x8*)(ldsb + acur + (o) + (m)*2048))
#define RD_B(n, o)   (*(const bf16x8*)(ldsb + bcur + (o) + (n)*2048))
#define MFMA(d, va, vb) d = __builtin_amdgcn_mfma_f32_16x16x32_bf16(va, vb, d, 0, 0, 0)
#define STAGEI(i, kel, sl) \
    __builtin_amdgcn_global_load_lds((glb_u8*)(gsrc[i] + (kel)), \
        (lds_u8*)(ldsb + ldst[i] + (uint32_t)(sl) * smul[i]), 16, 0, 0)

template <int UPG, int TMODE>
__global__ __launch_bounds__(640, 1) void bl_gemm(
    const unsigned short* __restrict__ A,   // [4096][K] bf16
    const unsigned short* __restrict__ B,   // [2048][K] bf16
    const float* __restrict__ bias,         // [2048]
    unsigned short* __restrict__ C,         // [4096][2048] bf16
    int K,
    const float* __restrict__ tmu, const float* __restrict__ tls,
    const float* __restrict__ teps, void* __restrict__ tdst)
{
    __shared__ unsigned short lds[49152];   // 96 KB
    uint8_t* ldsb = (uint8_t*)lds;

    const int tid  = threadIdx.x;
    const int wave = tid >> 6;
    const int lane = tid & 63;
    const int NT = K >> 6;

    if (wave < 8) {
        // ================= GEMM path (waves 0-7) =================
        const int swz = ((blockIdx.x & 7) << 5) | (blockIdx.x >> 3);
        const int bm = swz >> 4;
        const int bn = swz & 15;
        const int wr = wave >> 1;
        const int wc = wave & 1;

        const int lr8 = lane >> 3;
        const int ss  = (lane & 7) ^ lr8;
        const unsigned short* gsrc[6];
        uint32_t ldst[6], smul[6];
        #pragma unroll
        for (int i = 0; i < 6; ++i) {
            const int c = wave * 6 + i;
            if (c < 32) {
                gsrc[i] = A + (size_t)(bm * 256 + c * 8 + lr8) * K + ss * 8;
                ldst[i] = (uint32_t)c * 1024u;
                smul[i] = 32768u;
            } else {
                gsrc[i] = B + (size_t)(bn * 128 + (c - 32) * 8 + lr8) * K + ss * 8;
                ldst[i] = 65536u + (uint32_t)(c - 32) * 1024u;
                smul[i] = 16384u;
            }
        }

        const int rA = wr * 64 + (lane & 15);
        const int rB = wc * 64 + (lane & 15);
        const int ks = lane >> 4;
        const uint32_t aoff0 = (uint32_t)(rA * 128 + ((ks       ^ (rA & 7)) * 16));
        const uint32_t aoff1 = (uint32_t)(rA * 128 + (((4 | ks) ^ (rA & 7)) * 16));
        const uint32_t boff0 = (uint32_t)(rB * 128 + ((ks       ^ (rB & 7)) * 16));
        const uint32_t boff1 = (uint32_t)(rB * 128 + (((4 | ks) ^ (rB & 7)) * 16));

        f32x4 acc[4][4] = {};

        STAGEI(0, 0, 0); STAGEI(1, 0, 0); STAGEI(2, 0, 0);
        STAGEI(3, 0, 0); STAGEI(4, 0, 0); STAGEI(5, 0, 0);
        __syncthreads();                                         // sync #0

        for (int t = 0; t < NT; ++t) {
            const int cur = t & 1, nxt = cur ^ 1;
            const uint32_t acur = (uint32_t)cur * 32768u;
            const uint32_t bcur = 65536u + (uint32_t)cur * 16384u;
            const bool pf = (t + 1 < NT);
            const int ktn = (t + 1) << 6;

            bf16x8 a0, a1, a2, a3, b0, b1, b2, b3;

            // phase 0 (BAR x2)
            a0 = RD_A(0, aoff0); a1 = RD_A(1, aoff0);
            b0 = RD_B(0, boff0); b1 = RD_B(1, boff0); b2 = RD_B(2, boff0); b3 = RD_B(3, boff0);
            if (pf) { STAGEI(0, ktn, nxt); STAGEI(1, ktn, nxt); STAGEI(2, ktn, nxt); }
            BAR(); WAIT_LGKM0();
            __builtin_amdgcn_s_setprio(1);
            MFMA(acc[0][0], a0, b0); MFMA(acc[0][1], a0, b1); MFMA(acc[0][2], a0, b2); MFMA(acc[0][3], a0, b3);
            MFMA(acc[1][0], a1, b0); MFMA(acc[1][1], a1, b1); MFMA(acc[1][2], a1, b2); MFMA(acc[1][3], a1, b3);
            __builtin_amdgcn_s_setprio(0);
            BAR();

            // phase 1 (BAR x2)
            a2 = RD_A(2, aoff0); a3 = RD_A(3, aoff0);
            if (pf) { STAGEI(3, ktn, nxt); STAGEI(4, ktn, nxt); STAGEI(5, ktn, nxt); }
            BAR(); WAIT_LGKM0();
            __builtin_amdgcn_s_setprio(1);
            MFMA(acc[2][0], a2, b0); MFMA(acc[2][1], a2, b1); MFMA(acc[2][2], a2, b2); MFMA(acc[2][3], a2, b3);
            MFMA(acc[3][0], a3, b0); MFMA(acc[3][1], a3, b1); MFMA(acc[3][2], a3, b2); MFMA(acc[3][3], a3, b3);
            __builtin_amdgcn_s_setprio(0);
            BAR();

            // phase 2 (BAR x2)
            a0 = RD_A(0, aoff1); a1 = RD_A(1, aoff1);
            b0 = RD_B(0, boff1); b1 = RD_B(1, boff1); b2 = RD_B(2, boff1); b3 = RD_B(3, boff1);
            BAR(); WAIT_LGKM0();
            __builtin_amdgcn_s_setprio(1);
            MFMA(acc[0][0], a0, b0); MFMA(acc[0][1], a0, b1); MFMA(acc[0][2], a0, b2); MFMA(acc[0][3], a0, b3);
            MFMA(acc[1][0], a1, b0); MFMA(acc[1][1], a1, b1); MFMA(acc[1][2], a1, b2); MFMA(acc[1][3], a1, b3);
            __builtin_amdgcn_s_setprio(0);
            BAR();

            // phase 3 (BAR x1 + syncthreads)
            a2 = RD_A(2, aoff1); a3 = RD_A(3, aoff1);
            BAR(); WAIT_LGKM0();
            __builtin_amdgcn_s_setprio(1);
            MFMA(acc[2][0], a2, b0); MFMA(acc[2][1], a2, b1); MFMA(acc[2][2], a2, b2); MFMA(acc[2][3], a2, b3);
            MFMA(acc[3][0], a3, b0); MFMA(acc[3][1], a3, b1); MFMA(acc[3][2], a3, b2); MFMA(acc[3][3], a3, b3);
            __builtin_amdgcn_s_setprio(0);
            __syncthreads();
        }

        // epilogue
        const int col0 = bn * 128 + wc * 64 + (lane & 15);
        const int row0 = bm * 256 + wr * 64 + ((lane >> 4) << 2);
        #pragma unroll
        for (int n = 0; n < 4; ++n) {
            const int col = col0 + n * 16;
            const float bv = bias[col];
            #pragma unroll
            for (int m = 0; m < 4; ++m) {
                #pragma unroll
                for (int j = 0; j < 4; ++j) {
                    float v = acc[m][n][j] + bv;
                    v = v > 0.0f ? v : 0.0f;
                    C[(size_t)(row0 + m * 16 + j) * HID + col] = f2bf(v);
                }
            }
        }
    } else {
        // ================= transform path (waves 8-9, 128 threads) =============
        // MUST execute the same barrier sequence: sync, then per t: 7x BAR + sync.
        const int tw = tid - 512;                      // 0..127
        const float4* m4 = (const float4*)tmu;
        const float4* l4 = (const float4*)tls;
        const float4* e4 = (const float4*)teps;

        float4 pm[UPG], pl[UPG], pe[UPG];
        size_t base;
        if (TMODE == 0) {
            base = (size_t)blockIdx.x * 4096;          // units per block
            #pragma unroll
            for (int q = 0; q < UPG; ++q) {
                const size_t g = base + (size_t)q * 128 + tw;
                pm[q] = m4[g]; pl[q] = l4[g]; pe[q] = e4[g];
            }
        } else {
            base = (size_t)blockIdx.x * 200;           // head weights: 51200 units total
        }
        __syncthreads();                               // matches GEMM sync #0

        for (int t = 0; t < NT; ++t) {
            if (TMODE == 0) {
                ushort4* d4 = (ushort4*)tdst;
                #pragma unroll
                for (int q = 0; q < UPG; ++q) {
                    const size_t g = base + ((size_t)t * UPG + q) * 128 + tw;
                    ushort4 r;
                    r.x = f2bf(pm[q].x + __expf(pl[q].x) * pe[q].x);
                    r.y = f2bf(pm[q].y + __expf(pl[q].y) * pe[q].y);
                    r.z = f2bf(pm[q].z + __expf(pl[q].z) * pe[q].z);
                    r.w = f2bf(pm[q].w + __expf(pl[q].w) * pe[q].w);
                    d4[g] = r;
                }
                if (t + 1 < NT) {
                    #pragma unroll
                    for (int q = 0; q < UPG; ++q) {
                        const size_t g2 = base + ((size_t)(t + 1) * UPG + q) * 128 + tw;
                        pm[q] = m4[g2]; pl[q] = l4[g2]; pe[q] = e4[g2];
                    }
                }
            } else {
                const int lo = t * 128 + tw;
                if (lo < 200) {
                    const size_t g = base + lo;
                    const float4 m = m4[g], l = l4[g], e = e4[g];
                    float4 r;
                    r.x = m.x + __expf(l.x) * e.x;
                    r.y = m.y + __expf(l.y) * e.y;
                    r.z = m.z + __expf(l.z) * e.z;
                    r.w = m.w + __expf(l.w) * e.w;
                    ((float4*)tdst)[g] = r;
                }
            }
            BAR(); BAR(); BAR(); BAR(); BAR(); BAR(); BAR();
            __syncthreads();
        }
        // no barriers in GEMM epilogue -> none here
    }
}

// ---------------- head ----------------
__global__ __launch_bounds__(256) void bl_head(
    const unsigned short* __restrict__ h,   // [4096][2048] bf16
    const float* __restrict__ hw,           // [10][10][2048] f32
    const float* __restrict__ hb,           // [10][10] f32
    const int* __restrict__ task,           // [4096] i32
    float* __restrict__ out)                // [4096][10] f32
{
    const int wave = threadIdx.x >> 6, lane = threadIdx.x & 63;
    const int b = blockIdx.x * 4 + wave;
    const int t = task[b];
    const float* w = hw + (size_t)t * OUT_DIM * HID;
    const unsigned short* hr = h + (size_t)b * HID;

    float acc[OUT_DIM];
    #pragma unroll
    for (int o = 0; o < OUT_DIM; ++o) acc[o] = 0.0f;

    #pragma unroll
    for (int i = 0; i < HID / 512; ++i) {
        const int k0 = (i * 64 + lane) * 8;
        const bf16x8 hv8 = *(const bf16x8*)(hr + k0);
        float hf[8];
        #pragma unroll
        for (int j = 0; j < 8; ++j) hf[j] = (float)hv8[j];
        #pragma unroll
        for (int o = 0; o < OUT_DIM; ++o) {
            const float4 w0 = *(const float4*)(w + (size_t)o * HID + k0);
            const float4 w1 = *(const float4*)(w + (size_t)o * HID + k0 + 4);
            acc[o] += hf[0]*w0.x + hf[1]*w0.y + hf[2]*w0.z + hf[3]*w0.w
                    + hf[4]*w1.x + hf[5]*w1.y + hf[6]*w1.z + hf[7]*w1.w;
        }
    }
    #pragma unroll
    for (int o = 0; o < OUT_DIM; ++o) {
        float v = acc[o];
        #pragma unroll
        for (int s = 32; s > 0; s >>= 1) v += __shfl_down(v, s, 64);
        if (lane == 0) out[(size_t)b * OUT_DIM + o] = v + hb[t * OUT_DIM + o];
    }
}

// ---------------- launch ----------------

extern "C" void kernel_launch(void* const* d_in, const int* in_sizes, int n_in,
                              void* d_out, int out_size, void* d_ws, size_t ws_size,
                              hipStream_t stream)
{
    const float* x      = (const float*)d_in[0];
    const float* mu_w0  = (const float*)d_in[1];
    const float* ls_w0  = (const float*)d_in[2];
    const float* mu_b0  = (const float*)d_in[3];
    const float* ls_b0  = (const float*)d_in[4];
    const float* mu_w   = (const float*)d_in[5];
    const float* ls_w   = (const float*)d_in[6];
    const float* mu_b   = (const float*)d_in[7];
    const float* ls_b   = (const float*)d_in[8];
    const float* mu_hw  = (const float*)d_in[9];
    const float* ls_hw  = (const float*)d_in[10];
    const float* mu_hb  = (const float*)d_in[11];
    const float* ls_hb  = (const float*)d_in[12];
    const float* eps_w0 = (const float*)d_in[13];
    const float* eps_b0 = (const float*)d_in[14];
    const float* eps_w  = (const float*)d_in[15];
    const float* eps_b  = (const float*)d_in[16];
    const float* eps_hw = (const float*)d_in[17];
    const float* eps_hb = (const float*)d_in[18];
    const int*   task   = (const int*)d_in[19];

    uint8_t* ws = (uint8_t*)d_ws;
    constexpr size_t HH     = (size_t)HID * HID;
    constexpr size_t X_OFF  = 0;
    constexpr size_t W0_OFF = X_OFF  + (size_t)BATCH * IN_DIM * 2;       // x bf16
    constexpr size_t W_OFF  = W0_OFF + (size_t)HID * IN_DIM * 2;         // w0 bf16
    constexpr size_t H0_OFF = W_OFF  + 3 * HH * 2;                       // w1..3 bf16
    constexpr size_t H1_OFF = H0_OFF + (size_t)BATCH * HID * 2;          // h ping
    constexpr size_t B_OFF  = H1_OFF + (size_t)BATCH * HID * 2;          // h pong
    constexpr size_t HW_OFF = B_OFF  + (size_t)4 * HID * 4;              // biases f32
    constexpr size_t HB_OFF = HW_OFF + (size_t)NTASKS * OUT_DIM * HID * 4;

    unsigned short* xbf = (unsigned short*)(ws + X_OFF);
    unsigned short* w0b = (unsigned short*)(ws + W0_OFF);
    unsigned short* wb  = (unsigned short*)(ws + W_OFF);
    unsigned short* h0  = (unsigned short*)(ws + H0_OFF);
    unsigned short* h1  = (unsigned short*)(ws + H1_OFF);
    float* ball = (float*)(ws + B_OFF);
    float* hwf  = (float*)(ws + HW_OFF);
    float* hbf  = (float*)(ws + HB_OFF);

    bl_cvt<<<BATCH * IN_DIM / 4096, 256, 0, stream>>>((const float4*)x, (uint4*)xbf);
    bl_transform<<<HID * IN_DIM / 4096, 256, 0, stream>>>(
        (const float4*)mu_w0, (const float4*)ls_w0, (const float4*)eps_w0, (uint4*)w0b);
    bl_small<<<(4 * HID + NTASKS * OUT_DIM + 255) / 256, 256, 0, stream>>>(
        mu_b0, ls_b0, eps_b0, mu_b, ls_b, eps_b, mu_hb, ls_hb, eps_hb, ball, hbf);

    // GEMM_i fuses the transform of layer i+1's weights (or head weights).
    bl_gemm<2, 0><<<256, 640, 0, stream>>>(xbf, w0b, ball, h0, IN_DIM,
        mu_w, ls_w, eps_w, (void*)wb);                               // w1 (NT=16, upg=2)
    bl_gemm<1, 0><<<256, 640, 0, stream>>>(h0, wb, ball + HID, h1, HID,
        mu_w + HH, ls_w + HH, eps_w + HH, (void*)(wb + HH));         // w2
    bl_gemm<1, 0><<<256, 640, 0, stream>>>(h1, wb + HH, ball + 2 * HID, h0, HID,
        mu_w + 2 * HH, ls_w + 2 * HH, eps_w + 2 * HH, (void*)(wb + 2 * HH)); // w3
    bl_gemm<1, 1><<<256, 640, 0, stream>>>(h0, wb + 2 * HH, ball + 3 * HID, h1, HID,
        mu_hw, ls_hw, eps_hw, (void*)hwf);                           // head weights f32

    bl_head<<<BATCH / 4, 256, 0, stream>>>(h1, hwf, hbf, task, (float*)d_out);
}